// Round 6
// baseline (415.003 us; speedup 1.0000x reference)
//
#include <hip/hip_runtime.h>
#include <hip/hip_bf16.h>

#define BB 64
#define TT 1024
#define DD 512
#define NS 24

#define POT_OFF   65536
#define LENS_OFF  1638400
#define TRANS_OFF 1638464

// ---------------------------------------------------------------------------
// Kernel 1: pot = x @ W + b (+ boundary adds).
// 1024 blocks x 256 threads (4 waves, 4 blocks/CU). Wave q owns K-quarter q
// of the block's 64 rows. Per 32-K sub-chunk:
//   - coalesced global loads: 8 instrs, each 8 rows x 128 B fully consumed
//   - wave-private LDS transpose (stride 34 -> ~2-way conflicts, b64 ops)
//   - lane l consumes row l: ds_read_b64 + FMA with scalar-addressed W
// No __syncthreads in the K-loop: producer wave == consumer wave.
// ---------------------------------------------------------------------------
__global__ __launch_bounds__(256, 4) void gemm_pot(
    const float* __restrict__ x, const float* __restrict__ W,
    const float* __restrict__ bias, const float* __restrict__ trans,
    const float* __restrict__ lb, const float* __restrict__ rb,
    float* __restrict__ out)
{
  __shared__ float xs[4 * 64 * 34];          // 34,816 B, region per wave
  const int tid  = threadIdx.x;
  const int l    = tid & 63;
  const int q    = __builtin_amdgcn_readfirstlane(tid >> 6);  // wave-uniform
  const int row0 = blockIdx.x * 64;
  const int row  = row0 + l;
  float* xq = &xs[q * 64 * 34];

  const int r8 = l >> 3;                     // row-group 0..7
  const int c4 = l & 7;                      // float4 column within chunk

  float acc[NS];
#pragma unroll
  for (int nn = 0; nn < NS; ++nn) acc[nn] = 0.f;

#pragma unroll
  for (int s = 0; s < 4; ++s) {
    const int ko = q * 128 + s * 32;         // wave-uniform K offset

    // coalesced global loads: rows r8+8i, columns c4*4..c4*4+3
    float4 buf[8];
#pragma unroll
    for (int i = 0; i < 8; ++i) {
      const int ri = r8 + i * 8;
      buf[i] = *(const float4*)(x + (size_t)(row0 + ri) * DD + ko + c4 * 4);
    }
    // LDS transpose (b64 writes, stride 34)
#pragma unroll
    for (int i = 0; i < 8; ++i) {
      const int ri = r8 + i * 8;
      *(float2*)(&xq[ri * 34 + c4 * 4])     = make_float2(buf[i].x, buf[i].y);
      *(float2*)(&xq[ri * 34 + c4 * 4 + 2]) = make_float2(buf[i].z, buf[i].w);
    }
    // consume own row l (b64 reads; 2-way bank aliasing = free)
#pragma unroll
    for (int kk = 0; kk < 32; kk += 2) {
      float2 xv = *(const float2*)(&xq[l * 34 + kk]);
      const float* Wr = W + (size_t)(ko + kk) * NS;     // scalar -> s_load
#pragma unroll
      for (int nn = 0; nn < NS; ++nn) acc[nn] = fmaf(xv.x, Wr[nn],      acc[nn]);
#pragma unroll
      for (int nn = 0; nn < NS; ++nn) acc[nn] = fmaf(xv.y, Wr[NS + nn], acc[nn]);
    }
  }

  // reduce the 4 K-quarter partials through the (now free) LDS regions
  __syncthreads();
  if (q != 0) {
#pragma unroll
    for (int nn = 0; nn < NS; ++nn) xq[l * 34 + nn] = acc[nn];
  }
  __syncthreads();
  if (q == 0) {
    const int t = row & (TT - 1);
#pragma unroll
    for (int nn = 0; nn < NS; ++nn)
      acc[nn] += xs[1 * 64 * 34 + l * 34 + nn] + xs[2 * 64 * 34 + l * 34 + nn]
               + xs[3 * 64 * 34 + l * 34 + nn] + bias[nn];
    if (t == 0) {
#pragma unroll
      for (int nn = 0; nn < NS; ++nn) acc[nn] += lb[nn];
    }
    if (t == TT - 1) {
#pragma unroll
      for (int nn = 0; nn < NS; ++nn) acc[nn] += rb[nn];
    }
    float* po = out + POT_OFF + (size_t)row * NS;
#pragma unroll
    for (int i = 0; i < 6; ++i)
      *(float4*)(po + i * 4) = make_float4(acc[4*i], acc[4*i+1], acc[4*i+2], acc[4*i+3]);
  }

  if (blockIdx.x == 0 && tid < BB) out[LENS_OFF + tid] = (float)TT;
  if (blockIdx.x == 1) {
    for (int i = tid; i < NS * NS; i += 256) out[TRANS_OFF + i] = trans[i];
  }
}

// ---------------------------------------------------------------------------
// Kernel 2 (fused): scan + bp + backtrace, one block per batch, 1024 threads.
// Scan: wave 0, lanes 0..23. Alpha broadcast via single ds_write + 6
// same-address ds_read_b128 (best measured variant: ~161 us). Alpha
// overwrites pot in place in LDS; no barrier inside the scan loop.
// ---------------------------------------------------------------------------
__global__ __launch_bounds__(1024) void viterbi_fused(
    const float* __restrict__ pot, const float* __restrict__ trans,
    float* __restrict__ out_dec)
{
  __shared__ float ps[(TT + 8) * NS];     // pot rows, overwritten by alpha
  __shared__ unsigned char bl[TT * NS];   // backpointers
  __shared__ float tl[NS * NS];           // trans
  __shared__ int H[32][NS];
  __shared__ int e[32];

  const int b = blockIdx.x, tid = threadIdx.x;

  // ---- stage pot[b] + trans ----
  {
    const float4* src = (const float4*)(pot + (size_t)b * TT * NS);
    float4* dst = (float4*)ps;
#pragma unroll
    for (int i = 0; i < 6; ++i) dst[tid + i * 1024] = src[tid + i * 1024];
    if (tid < NS * NS) tl[tid] = trans[tid];
  }
  __syncthreads();

  // ---- forward scan ----
  if (tid < 24) {
    const int n = tid;
    float tc[NS];
#pragma unroll
    for (int m = 0; m < NS; ++m) tc[m] = tl[m * NS + n];

    float as_[NS];                       // alpha row, replicated in all lanes
    {
      const float4* ar = (const float4*)ps;   // row 0 == alpha0
#pragma unroll
      for (int i = 0; i < 6; ++i) {
        float4 v = ar[i];
        as_[4*i] = v.x; as_[4*i+1] = v.y; as_[4*i+2] = v.z; as_[4*i+3] = v.w;
      }
    }

    float pv[8];
#pragma unroll
    for (int u = 0; u < 8; ++u) pv[u] = ps[(1 + u) * NS + n];

    auto step = [&](int tt, float potv) {
      float sc[NS];
#pragma unroll
      for (int m = 0; m < NS; ++m) sc[m] = as_[m] + tc[m];
      float r0 = fmaxf(fmaxf(sc[0],  sc[1]),  sc[2]);
      float r1 = fmaxf(fmaxf(sc[3],  sc[4]),  sc[5]);
      float r2 = fmaxf(fmaxf(sc[6],  sc[7]),  sc[8]);
      float r3 = fmaxf(fmaxf(sc[9],  sc[10]), sc[11]);
      float r4 = fmaxf(fmaxf(sc[12], sc[13]), sc[14]);
      float r5 = fmaxf(fmaxf(sc[15], sc[16]), sc[17]);
      float r6 = fmaxf(fmaxf(sc[18], sc[19]), sc[20]);
      float r7 = fmaxf(fmaxf(sc[21], sc[22]), sc[23]);
      float q0 = fmaxf(fmaxf(r0, r1), r2);
      float q1 = fmaxf(fmaxf(r3, r4), r5);
      float q2 = fmaxf(r6, r7);
      float best = fmaxf(fmaxf(q0, q1), q2);
      float anew = best + potv;
      ps[tt * NS + n] = anew;            // 24 lanes write the row...
      const float4* ar = (const float4*)(ps + tt * NS);
#pragma unroll
      for (int i = 0; i < 6; ++i) {      // ...then broadcast-read it back
        float4 v = ar[i];                // (same wave: in-order, no barrier)
        as_[4*i] = v.x; as_[4*i+1] = v.y; as_[4*i+2] = v.z; as_[4*i+3] = v.w;
      }
    };

    for (int t = 1; t + 7 <= TT - 1; t += 8) {
#pragma unroll
      for (int u = 0; u < 8; ++u) {
        const int tt = t + u;
        const float potv = pv[u];
        pv[u] = ps[(tt + 8) * NS + n];   // 8 ahead of the overwrite frontier
        step(tt, potv);
      }
    }
#pragma unroll
    for (int u = 0; u < 7; ++u) step(1017 + u, pv[u]);
  }
  __syncthreads();

  // ---- bp build from LDS alphas (bit-exact, first-max strict >) ----
  for (int idx = tid; idx < (TT - 1) * NS; idx += 1024) {
    const int n = idx % NS;
    const int t = idx / NS + 1;
    const float* ar = &ps[(t - 1) * NS];
    float best = ar[0] + tl[n];
    int bi = 0;
#pragma unroll
    for (int m = 1; m < NS; ++m) {
      float s = ar[m] + tl[m * NS + n];
      bool g = s > best;
      bi = g ? m : bi;
      best = g ? s : best;
    }
    bl[t * NS + n] = (unsigned char)bi;
  }
  __syncthreads();

  // ---- backtrace: chunk composition (C=32) ----
  if (tid < 32 * NS) {
    const int c = tid / NS, s = tid % NS;
    int a = s;
    int tlo = c * 32; if (tlo < 1) tlo = 1;
    for (int t = c * 32 + 31; t >= tlo; --t) a = bl[t * NS + a];
    H[c][s] = a;
  }
  __syncthreads();

  if (tid == 0) {
    const float* ar = &ps[(TT - 1) * NS];
    float best = ar[0]; int bi = 0;
#pragma unroll
    for (int nn = 1; nn < NS; ++nn) {
      float v = ar[nn];
      if (v > best) { best = v; bi = nn; }
    }
    int tag = bi;
    e[31] = tag;
    for (int c = 31; c >= 1; --c) { tag = H[c][tag]; e[c - 1] = tag; }
  }
  __syncthreads();

  if (tid < 32) {
    const int c = tid;
    int tag = e[c];
    float* od = out_dec + (size_t)b * TT;
    od[c * 32 + 31] = (float)tag;
    for (int t = c * 32 + 30; t >= c * 32; --t) {
      tag = bl[(t + 1) * NS + tag];
      od[t] = (float)tag;
    }
  }
}

// ---------------------------------------------------------------------------
extern "C" void kernel_launch(void* const* d_in, const int* in_sizes, int n_in,
                              void* d_out, int out_size, void* d_ws, size_t ws_size,
                              hipStream_t stream)
{
  const float* x     = (const float*)d_in[0];
  const float* W     = (const float*)d_in[1];
  const float* bias  = (const float*)d_in[2];
  const float* trans = (const float*)d_in[3];
  const float* lb    = (const float*)d_in[4];
  const float* rb    = (const float*)d_in[5];
  float* out = (float*)d_out;

  gemm_pot<<<1024, 256, 0, stream>>>(x, W, bias, trans, lb, rb, out);
  viterbi_fused<<<BB, 1024, 0, stream>>>(out + POT_OFF, trans, out);
}

// Round 7
// 382.611 us; speedup vs baseline: 1.0847x; 1.0847x over previous
//
#include <hip/hip_runtime.h>
#include <hip/hip_bf16.h>

#define BB 64
#define TT 1024
#define DD 512
#define NS 24

#define POT_OFF   65536
#define LENS_OFF  1638400
#define TRANS_OFF 1638464

// ---------------------------------------------------------------------------
// Kernel 1: pot = x @ W + b (+ boundary adds). MLP-maximized streaming:
// 1024 blocks x 256 threads (4 waves/SIMD). Thread (lane l, wave q) owns
// K-quarter q of row blk*64+l = 32 float4 loads, issued through a 16-deep
// rolling window (16 upfront, reload 4 after consuming 4) so each lane keeps
// 12-16 dwordx4 in flight -> ~200+ lines outstanding per CU (Little's law
// needs ~72 for 6.3 TB/s at ~900cyc latency). W addressing is wave-uniform
// (readfirstlane q) -> s_load broadcast, 1 VALU per MAC.
// ---------------------------------------------------------------------------
__global__ __launch_bounds__(256, 4) void gemm_pot(
    const float* __restrict__ x, const float* __restrict__ W,
    const float* __restrict__ bias, const float* __restrict__ trans,
    const float* __restrict__ lb, const float* __restrict__ rb,
    float* __restrict__ out)
{
  __shared__ float red[3][64][25];     // stride 25: coprime with 32 banks
  const int tid = threadIdx.x;
  const int l   = tid & 63;
  const int q   = __builtin_amdgcn_readfirstlane(tid >> 6);  // wave-uniform
  const int row = blockIdx.x * 64 + l;

  const float4* xp = (const float4*)(x + (size_t)row * DD + q * 128);

  float acc[NS];
#pragma unroll
  for (int nn = 0; nn < NS; ++nn) acc[nn] = 0.f;

  // 16-deep load window over the 32 float4s of this K-quarter
  float4 buf[16];
#pragma unroll
  for (int i = 0; i < 16; ++i) buf[i] = xp[i];

#pragma unroll
  for (int c = 0; c < 8; ++c) {
#pragma unroll
    for (int i = 0; i < 4; ++i) {
      const int f = c * 4 + i;          // float4 index 0..31
      const int s = f & 15;             // window slot
      float4 v = buf[s];
      if (f + 16 < 32) buf[s] = xp[f + 16];   // refill window (independent)
      const float* Wr = W + (size_t)(q * 128 + f * 4) * NS;  // scalar addr
      const float x0 = v.x, x1 = v.y, x2 = v.z, x3 = v.w;
#pragma unroll
      for (int nn = 0; nn < NS; ++nn) acc[nn] = fmaf(x0, Wr[nn],          acc[nn]);
#pragma unroll
      for (int nn = 0; nn < NS; ++nn) acc[nn] = fmaf(x1, Wr[NS + nn],     acc[nn]);
#pragma unroll
      for (int nn = 0; nn < NS; ++nn) acc[nn] = fmaf(x2, Wr[2 * NS + nn], acc[nn]);
#pragma unroll
      for (int nn = 0; nn < NS; ++nn) acc[nn] = fmaf(x3, Wr[3 * NS + nn], acc[nn]);
    }
  }

  // reduce 4 K-quarter partials
  if (q != 0) {
#pragma unroll
    for (int nn = 0; nn < NS; ++nn) red[q - 1][l][nn] = acc[nn];
  }
  __syncthreads();
  if (q == 0) {
    const int t = row & (TT - 1);
#pragma unroll
    for (int nn = 0; nn < NS; ++nn)
      acc[nn] += red[0][l][nn] + red[1][l][nn] + red[2][l][nn] + bias[nn];
    if (t == 0) {
#pragma unroll
      for (int nn = 0; nn < NS; ++nn) acc[nn] += lb[nn];
    }
    if (t == TT - 1) {
#pragma unroll
      for (int nn = 0; nn < NS; ++nn) acc[nn] += rb[nn];
    }
    float* po = out + POT_OFF + (size_t)row * NS;
#pragma unroll
    for (int i = 0; i < 6; ++i)
      *(float4*)(po + i * 4) = make_float4(acc[4*i], acc[4*i+1], acc[4*i+2], acc[4*i+3]);
  }

  if (blockIdx.x == 0 && tid < BB) out[LENS_OFF + tid] = (float)TT;
  if (blockIdx.x == 1) {
    for (int i = tid; i < NS * NS; i += 256) out[TRANS_OFF + i] = trans[i];
  }
}

// ---------------------------------------------------------------------------
// Kernel 2 (fused): scan + bp + backtrace, one block per batch, 1024 threads.
// UNCHANGED from R5 (control): ~162 us, ~340 cyc/step LDS round-trip floor.
// ---------------------------------------------------------------------------
__global__ __launch_bounds__(1024) void viterbi_fused(
    const float* __restrict__ pot, const float* __restrict__ trans,
    float* __restrict__ out_dec)
{
  __shared__ float ps[(TT + 8) * NS];     // pot rows, overwritten by alpha
  __shared__ unsigned char bl[TT * NS];   // backpointers
  __shared__ float tl[NS * NS];           // trans
  __shared__ int H[32][NS];
  __shared__ int e[32];

  const int b = blockIdx.x, tid = threadIdx.x;

  // ---- stage pot[b] + trans ----
  {
    const float4* src = (const float4*)(pot + (size_t)b * TT * NS);
    float4* dst = (float4*)ps;
#pragma unroll
    for (int i = 0; i < 6; ++i) dst[tid + i * 1024] = src[tid + i * 1024];
    if (tid < NS * NS) tl[tid] = trans[tid];
  }
  __syncthreads();

  // ---- forward scan ----
  if (tid < 24) {
    const int n = tid;
    float tc[NS];
#pragma unroll
    for (int m = 0; m < NS; ++m) tc[m] = tl[m * NS + n];

    float as_[NS];                       // alpha row, replicated in all lanes
    {
      const float4* ar = (const float4*)ps;   // row 0 == alpha0
#pragma unroll
      for (int i = 0; i < 6; ++i) {
        float4 v = ar[i];
        as_[4*i] = v.x; as_[4*i+1] = v.y; as_[4*i+2] = v.z; as_[4*i+3] = v.w;
      }
    }

    float pv[8];
#pragma unroll
    for (int u = 0; u < 8; ++u) pv[u] = ps[(1 + u) * NS + n];

    auto step = [&](int tt, float potv) {
      float sc[NS];
#pragma unroll
      for (int m = 0; m < NS; ++m) sc[m] = as_[m] + tc[m];
      float r0 = fmaxf(fmaxf(sc[0],  sc[1]),  sc[2]);
      float r1 = fmaxf(fmaxf(sc[3],  sc[4]),  sc[5]);
      float r2 = fmaxf(fmaxf(sc[6],  sc[7]),  sc[8]);
      float r3 = fmaxf(fmaxf(sc[9],  sc[10]), sc[11]);
      float r4 = fmaxf(fmaxf(sc[12], sc[13]), sc[14]);
      float r5 = fmaxf(fmaxf(sc[15], sc[16]), sc[17]);
      float r6 = fmaxf(fmaxf(sc[18], sc[19]), sc[20]);
      float r7 = fmaxf(fmaxf(sc[21], sc[22]), sc[23]);
      float q0 = fmaxf(fmaxf(r0, r1), r2);
      float q1 = fmaxf(fmaxf(r3, r4), r5);
      float q2 = fmaxf(r6, r7);
      float best = fmaxf(fmaxf(q0, q1), q2);
      float anew = best + potv;
      ps[tt * NS + n] = anew;            // 24 lanes write the row...
      const float4* ar = (const float4*)(ps + tt * NS);
#pragma unroll
      for (int i = 0; i < 6; ++i) {      // ...then broadcast-read it back
        float4 v = ar[i];                // (same wave: in-order, no barrier)
        as_[4*i] = v.x; as_[4*i+1] = v.y; as_[4*i+2] = v.z; as_[4*i+3] = v.w;
      }
    };

    for (int t = 1; t + 7 <= TT - 1; t += 8) {
#pragma unroll
      for (int u = 0; u < 8; ++u) {
        const int tt = t + u;
        const float potv = pv[u];
        pv[u] = ps[(tt + 8) * NS + n];   // 8 ahead of the overwrite frontier
        step(tt, potv);
      }
    }
#pragma unroll
    for (int u = 0; u < 7; ++u) step(1017 + u, pv[u]);
  }
  __syncthreads();

  // ---- bp build from LDS alphas (bit-exact, first-max strict >) ----
  for (int idx = tid; idx < (TT - 1) * NS; idx += 1024) {
    const int n = idx % NS;
    const int t = idx / NS + 1;
    const float* ar = &ps[(t - 1) * NS];
    float best = ar[0] + tl[n];
    int bi = 0;
#pragma unroll
    for (int m = 1; m < NS; ++m) {
      float s = ar[m] + tl[m * NS + n];
      bool g = s > best;
      bi = g ? m : bi;
      best = g ? s : best;
    }
    bl[t * NS + n] = (unsigned char)bi;
  }
  __syncthreads();

  // ---- backtrace: chunk composition (C=32) ----
  if (tid < 32 * NS) {
    const int c = tid / NS, s = tid % NS;
    int a = s;
    int tlo = c * 32; if (tlo < 1) tlo = 1;
    for (int t = c * 32 + 31; t >= tlo; --t) a = bl[t * NS + a];
    H[c][s] = a;
  }
  __syncthreads();

  if (tid == 0) {
    const float* ar = &ps[(TT - 1) * NS];
    float best = ar[0]; int bi = 0;
#pragma unroll
    for (int nn = 1; nn < NS; ++nn) {
      float v = ar[nn];
      if (v > best) { best = v; bi = nn; }
    }
    int tag = bi;
    e[31] = tag;
    for (int c = 31; c >= 1; --c) { tag = H[c][tag]; e[c - 1] = tag; }
  }
  __syncthreads();

  if (tid < 32) {
    const int c = tid;
    int tag = e[c];
    float* od = out_dec + (size_t)b * TT;
    od[c * 32 + 31] = (float)tag;
    for (int t = c * 32 + 30; t >= c * 32; --t) {
      tag = bl[(t + 1) * NS + tag];
      od[t] = (float)tag;
    }
  }
}

// ---------------------------------------------------------------------------
extern "C" void kernel_launch(void* const* d_in, const int* in_sizes, int n_in,
                              void* d_out, int out_size, void* d_ws, size_t ws_size,
                              hipStream_t stream)
{
  const float* x     = (const float*)d_in[0];
  const float* W     = (const float*)d_in[1];
  const float* bias  = (const float*)d_in[2];
  const float* trans = (const float*)d_in[3];
  const float* lb    = (const float*)d_in[4];
  const float* rb    = (const float*)d_in[5];
  float* out = (float*)d_out;

  gemm_pot<<<1024, 256, 0, stream>>>(x, W, bias, trans, lb, rb, out);
  viterbi_fused<<<BB, 1024, 0, stream>>>(out + POT_OFF, trans, out);
}

// Round 8
// 330.534 us; speedup vs baseline: 1.2556x; 1.1576x over previous
//
#include <hip/hip_runtime.h>
#include <hip/hip_bf16.h>

#define BB 64
#define TT 1024
#define DD 512
#define NS 24

#define POT_OFF   65536
#define LENS_OFF  1638400
#define TRANS_OFF 1638464

// ---------------------------------------------------------------------------
// Kernel 1: pot = x @ W + b (+ boundary adds).
// W (48 KB) staged ONCE per block into LDS; all FMAs read W rows via
// same-address ds_read_b128 broadcast (conflict-free). x streamed per-lane
// with an 8-deep rolling b128 window. 1024 blocks x 256 threads; wave q owns
// K-quarter q of the block's 64 rows (16 waves of work, 3 blocks/CU by LDS).
// Partial reduction reuses W's LDS region after a barrier.
// ---------------------------------------------------------------------------
__global__ __launch_bounds__(256) void gemm_pot(
    const float* __restrict__ x, const float* __restrict__ W,
    const float* __restrict__ bias, const float* __restrict__ trans,
    const float* __restrict__ lb, const float* __restrict__ rb,
    float* __restrict__ out)
{
  __shared__ float wl[DD * NS];              // 49,152 B: W, then partials
  const int tid = threadIdx.x;
  const int l   = tid & 63;
  const int q   = tid >> 6;                  // K-quarter
  const int row = blockIdx.x * 64 + l;

  // stage W: 12288 floats = 256 threads x 12 float4, coalesced
  {
    const float4* Ws = (const float4*)W;
    float4* Wd = (float4*)wl;
#pragma unroll
    for (int i = 0; i < 12; ++i) Wd[tid + i * 256] = Ws[tid + i * 256];
  }
  __syncthreads();

  const float4* xp = (const float4*)(x + (size_t)row * DD + q * 128);

  float acc[NS];
#pragma unroll
  for (int nn = 0; nn < NS; ++nn) acc[nn] = 0.f;

  float4 buf[8];
#pragma unroll
  for (int i = 0; i < 8; ++i) buf[i] = xp[i];

#pragma unroll
  for (int f = 0; f < 32; ++f) {             // 32 float4 = 128 k per quarter
    float4 v = buf[f & 7];
    if (f + 8 < 32) buf[f & 7] = xp[f + 8];  // refill window
    const float xj[4] = {v.x, v.y, v.z, v.w};
#pragma unroll
    for (int j = 0; j < 4; ++j) {
      const int k = q * 128 + f * 4 + j;
      const float4* wr = (const float4*)&wl[k * NS];   // same addr all lanes
      float4 w0 = wr[0], w1 = wr[1], w2 = wr[2], w3 = wr[3], w4 = wr[4], w5 = wr[5];
      const float wv[NS] = {w0.x,w0.y,w0.z,w0.w, w1.x,w1.y,w1.z,w1.w,
                            w2.x,w2.y,w2.z,w2.w, w3.x,w3.y,w3.z,w3.w,
                            w4.x,w4.y,w4.z,w4.w, w5.x,w5.y,w5.z,w5.w};
      const float xv = xj[j];
#pragma unroll
      for (int nn = 0; nn < NS; ++nn) acc[nn] = fmaf(xv, wv[nn], acc[nn]);
    }
  }

  // reduce the 4 K-quarter partials through W's (now dead) LDS region
  __syncthreads();
  if (q != 0) {
#pragma unroll
    for (int nn = 0; nn < NS; ++nn) wl[((q - 1) * 64 + l) * 25 + nn] = acc[nn];
  }
  __syncthreads();
  if (q == 0) {
    const int t = row & (TT - 1);
#pragma unroll
    for (int nn = 0; nn < NS; ++nn)
      acc[nn] += wl[(0 * 64 + l) * 25 + nn] + wl[(1 * 64 + l) * 25 + nn]
               + wl[(2 * 64 + l) * 25 + nn] + bias[nn];
    if (t == 0) {
#pragma unroll
      for (int nn = 0; nn < NS; ++nn) acc[nn] += lb[nn];
    }
    if (t == TT - 1) {
#pragma unroll
      for (int nn = 0; nn < NS; ++nn) acc[nn] += rb[nn];
    }
    float* po = out + POT_OFF + (size_t)row * NS;
#pragma unroll
    for (int i = 0; i < 6; ++i)
      *(float4*)(po + i * 4) = make_float4(acc[4*i], acc[4*i+1], acc[4*i+2], acc[4*i+3]);
  }

  if (blockIdx.x == 0 && tid < BB) out[LENS_OFF + tid] = (float)TT;
  if (blockIdx.x == 1) {
    for (int i = tid; i < NS * NS; i += 256) out[TRANS_OFF + i] = trans[i];
  }
}

// ---------------------------------------------------------------------------
// Kernel 2 (fused): scan + bp + backtrace, one block per batch, 1024 threads.
// Scan: wave 0, lanes (g = tid>>5, n = tid&31 clamped to 23). 2-group
// m-split: each lane reduces 12 m's (4 max3 + 2 max), combine via ONE
// ds_bpermute, +pot single add (exact), write row, read back HALF row
// (3 x b128 same-addr broadcast). 5 DS ops/step vs 7 before.
// ---------------------------------------------------------------------------
__global__ __launch_bounds__(1024) void viterbi_fused(
    const float* __restrict__ pot, const float* __restrict__ trans,
    float* __restrict__ out_dec)
{
  __shared__ float ps[(TT + 8) * NS];     // pot rows, overwritten by alpha
  __shared__ unsigned char bl[TT * NS];   // backpointers
  __shared__ float tl[NS * NS];           // trans
  __shared__ int H[32][NS];
  __shared__ int e[32];

  const int b = blockIdx.x, tid = threadIdx.x;

  // ---- stage pot[b] + trans ----
  {
    const float4* src = (const float4*)(pot + (size_t)b * TT * NS);
    float4* dst = (float4*)ps;
#pragma unroll
    for (int i = 0; i < 6; ++i) dst[tid + i * 1024] = src[tid + i * 1024];
    if (tid < NS * NS) tl[tid] = trans[tid];
  }
  __syncthreads();

  // ---- forward scan: wave 0 only ----
  if (tid < 64) {
    const int g  = tid >> 5;               // m-group 0/1
    const int n0 = tid & 31;
    const int n  = (n0 < 24) ? n0 : 23;    // clamped lanes duplicate n=23

    float tc[12];
#pragma unroll
    for (int j = 0; j < 12; ++j) tc[j] = tl[(12 * g + j) * NS + n];

    float as12[12];
    {
      const float4* rr = (const float4*)&ps[12 * g];   // alpha0 half-row
#pragma unroll
      for (int i = 0; i < 3; ++i) {
        float4 v = rr[i];
        as12[4*i] = v.x; as12[4*i+1] = v.y; as12[4*i+2] = v.z; as12[4*i+3] = v.w;
      }
    }

    float pv[8];
#pragma unroll
    for (int u = 0; u < 8; ++u) pv[u] = ps[(1 + u) * NS + n];

    const int partner = (tid ^ 32) * 4;

    auto step = [&](int tt, float potv) {
      float sc[12];
#pragma unroll
      for (int j = 0; j < 12; ++j) sc[j] = as12[j] + tc[j];
      float p0 = fmaxf(fmaxf(sc[0], sc[1]),  sc[2]);
      float p1 = fmaxf(fmaxf(sc[3], sc[4]),  sc[5]);
      float p2 = fmaxf(fmaxf(sc[6], sc[7]),  sc[8]);
      float p3 = fmaxf(fmaxf(sc[9], sc[10]), sc[11]);
      float pm = fmaxf(fmaxf(p0, p1), fmaxf(p2, p3));
      float ot = __int_as_float(
          __builtin_amdgcn_ds_bpermute(partner, __float_as_int(pm)));
      float anew = fmaxf(pm, ot) + potv;   // exact: max assoc-free, one add
      ps[tt * NS + n] = anew;              // dup lanes write same value/addr
      const float4* rr = (const float4*)&ps[tt * NS + 12 * g];
#pragma unroll
      for (int i = 0; i < 3; ++i) {        // half-row readback, broadcast
        float4 v = rr[i];
        as12[4*i] = v.x; as12[4*i+1] = v.y; as12[4*i+2] = v.z; as12[4*i+3] = v.w;
      }
    };

    for (int t = 1; t + 7 <= TT - 1; t += 8) {
#pragma unroll
      for (int u = 0; u < 8; ++u) {
        const int tt = t + u;
        const float potv = pv[u];
        pv[u] = ps[(tt + 8) * NS + n];     // 8 ahead of overwrite frontier
        step(tt, potv);
      }
    }
#pragma unroll
    for (int u = 0; u < 7; ++u) step(1017 + u, pv[u]);
  }
  __syncthreads();

  // ---- bp build from LDS alphas (bit-exact, first-max strict >) ----
  for (int idx = tid; idx < (TT - 1) * NS; idx += 1024) {
    const int n = idx % NS;
    const int t = idx / NS + 1;
    const float* ar = &ps[(t - 1) * NS];
    float best = ar[0] + tl[n];
    int bi = 0;
#pragma unroll
    for (int m = 1; m < NS; ++m) {
      float s = ar[m] + tl[m * NS + n];
      bool g = s > best;
      bi = g ? m : bi;
      best = g ? s : best;
    }
    bl[t * NS + n] = (unsigned char)bi;
  }
  __syncthreads();

  // ---- backtrace: chunk composition (C=32) ----
  if (tid < 32 * NS) {
    const int c = tid / NS, s = tid % NS;
    int a = s;
    int tlo = c * 32; if (tlo < 1) tlo = 1;
    for (int t = c * 32 + 31; t >= tlo; --t) a = bl[t * NS + a];
    H[c][s] = a;
  }
  __syncthreads();

  if (tid == 0) {
    const float* ar = &ps[(TT - 1) * NS];
    float best = ar[0]; int bi = 0;
#pragma unroll
    for (int nn = 1; nn < NS; ++nn) {
      float v = ar[nn];
      if (v > best) { best = v; bi = nn; }
    }
    int tag = bi;
    e[31] = tag;
    for (int c = 31; c >= 1; --c) { tag = H[c][tag]; e[c - 1] = tag; }
  }
  __syncthreads();

  if (tid < 32) {
    const int c = tid;
    int tag = e[c];
    float* od = out_dec + (size_t)b * TT;
    od[c * 32 + 31] = (float)tag;
    for (int t = c * 32 + 30; t >= c * 32; --t) {
      tag = bl[(t + 1) * NS + tag];
      od[t] = (float)tag;
    }
  }
}

// ---------------------------------------------------------------------------
extern "C" void kernel_launch(void* const* d_in, const int* in_sizes, int n_in,
                              void* d_out, int out_size, void* d_ws, size_t ws_size,
                              hipStream_t stream)
{
  const float* x     = (const float*)d_in[0];
  const float* W     = (const float*)d_in[1];
  const float* bias  = (const float*)d_in[2];
  const float* trans = (const float*)d_in[3];
  const float* lb    = (const float*)d_in[4];
  const float* rb    = (const float*)d_in[5];
  float* out = (float*)d_out;

  gemm_pot<<<1024, 256, 0, stream>>>(x, W, bias, trans, lb, rb, out);
  viterbi_fused<<<BB, 1024, 0, stream>>>(out + POT_OFF, trans, out);
}